// Round 1
// baseline (14558.940 us; speedup 1.0000x reference)
//
#include <hip/hip_runtime.h>
#include <cmath>

#define NB 8
#define NN 20000
#define ND 128
#define NE_TOT 192000   /* 3 edge sets * 64000 edges, contiguous per batch */
#define NPASS 5

// Ping-pong node buffers + pooled accumulator as static device globals
// (no hipMalloc, no reliance on ws_size). Fully re-initialized every call.
__device__ float g_nodes0[(size_t)NB * NN * ND];
__device__ float g_nodes1[(size_t)NB * NN * ND];
__device__ float g_pooled[NB * ND];

__device__ __forceinline__ float* buf_ptr(int sel) {
    return sel == 0 ? g_nodes0 : g_nodes1;
}

// next = cur  (vectorized copy)
__global__ void copyK(const float* __restrict__ ext_src, int src_sel, int dst_sel) {
    const float4* __restrict__ s =
        (const float4*)(src_sel < 0 ? ext_src : buf_ptr(src_sel));
    float4* __restrict__ d = (float4*)buf_ptr(dst_sel);
    const size_t n4 = (size_t)NB * NN * ND / 4;
    for (size_t i = (size_t)blockIdx.x * blockDim.x + threadIdx.x; i < n4;
         i += (size_t)gridDim.x * blockDim.x)
        d[i] = s[i];
}

// next[dst] += cur[src] over all edges (32 lanes per edge, float4 per lane)
__global__ void scatterK(const float* __restrict__ ext_src, int src_sel, int dst_sel,
                         const int* __restrict__ edges) {
    const float* __restrict__ src = (src_sel < 0 ? ext_src : buf_ptr(src_sel));
    float* __restrict__ dst = buf_ptr(dst_sel);

    const int tid  = blockIdx.x * blockDim.x + threadIdx.x;
    const int eid  = tid >> 5;   // 32 lanes per edge
    const int lane = tid & 31;
    if (eid >= NB * NE_TOT) return;

    const int b = eid / NE_TOT;
    const int r = eid - b * NE_TOT;
    const int* ep = edges + ((size_t)b * NE_TOT + r) * 2;
    const int dn = ep[0];  // dst
    const int sn = ep[1];  // src

    const float4 v =
        ((const float4*)(src + ((size_t)b * NN + sn) * ND))[lane];
    float* dp = dst + ((size_t)b * NN + dn) * ND + lane * 4;
    unsafeAtomicAdd(dp + 0, v.x);
    unsafeAtomicAdd(dp + 1, v.y);
    unsafeAtomicAdd(dp + 2, v.z);
    unsafeAtomicAdd(dp + 3, v.w);
}

__global__ void zeroPooledK() {
    const int i = threadIdx.x;
    if (i < NB * ND) g_pooled[i] = 0.0f;
}

// pooled[b][d] = sum_n nodes[b][n][d]
__global__ void poolK(int src_sel) {
    const float* __restrict__ src = buf_ptr(src_sel);
    const int b = blockIdx.y;
    const int chunk = blockIdx.x;
    const int t = threadIdx.x;  // 0..127 == d
    const int r0 = chunk * 128;
    const int r1 = min(r0 + 128, NN);
    float s = 0.0f;
    for (int r = r0; r < r1; ++r)
        s += src[((size_t)b * NN + r) * ND + t];
    unsafeAtomicAdd(&g_pooled[b * ND + t], s);
}

// log / nan->0 / relu / inf->finite_max / concat / MLP head. Tiny; one block.
__global__ void headK(const float* __restrict__ ptype,
                      const float* __restrict__ w1, const float* __restrict__ b1,
                      const float* __restrict__ w2, const float* __restrict__ b2,
                      const float* __restrict__ w3, const float* __restrict__ b3,
                      float* __restrict__ out) {
    __shared__ float sx[NB][ND + 1];  // y (128) + problem_type (1)
    __shared__ float sh1[NB][80];
    __shared__ float sh2[NB][80];
    const int t = threadIdx.x;  // blockDim.x == 256

    for (int i = t; i < NB * ND; i += 256) {
        const int b = i >> 7, d = i & 127;
        float y = logf(g_pooled[i]);
        if (isnan(y)) y = 0.0f;        // nan -> 0
        y = fmaxf(y, 0.0f);            // relu (also folds -inf -> 0)
        sx[b][d] = y;
    }
    __syncthreads();

    if (t < NB) {
        float fm = -INFINITY;
        for (int d = 0; d < ND; ++d) {
            const float y = sx[t][d];
            if (!isinf(y)) fm = fmaxf(fm, y);
        }
        for (int d = 0; d < ND; ++d)
            if (isinf(sx[t][d])) sx[t][d] = fm;  // +inf -> finite_max
        sx[t][ND] = ptype[t];
    }
    __syncthreads();

    for (int i = t; i < NB * 80; i += 256) {
        const int b = i / 80, j = i - b * 80;
        float s = b1[j];
        for (int k = 0; k < ND + 1; ++k) s += sx[b][k] * w1[k * 80 + j];
        sh1[b][j] = s > 0.0f ? s : 0.01f * s;  // leaky_relu
    }
    __syncthreads();

    for (int i = t; i < NB * 80; i += 256) {
        const int b = i / 80, j = i - b * 80;
        float s = b2[j];
        for (int k = 0; k < 80; ++k) s += sh1[b][k] * w2[k * 80 + j];
        sh2[b][j] = s > 0.0f ? s : 0.01f * s;
    }
    __syncthreads();

    for (int i = t; i < NB * 10; i += 256) {
        const int b = i / 10, j = i - b * 10;
        float s = b3[j];
        for (int k = 0; k < 80; ++k) s += sh2[b][k] * w3[k * 10 + j];
        out[b * 10 + j] = s;
    }
}

extern "C" void kernel_launch(void* const* d_in, const int* in_sizes, int n_in,
                              void* d_out, int out_size, void* d_ws, size_t ws_size,
                              hipStream_t stream) {
    const float* nodes = (const float*)d_in[0];
    const float* ptype = (const float*)d_in[1];
    const float* w1    = (const float*)d_in[2];
    const float* b1    = (const float*)d_in[3];
    const float* w2    = (const float*)d_in[4];
    const float* b2    = (const float*)d_in[5];
    const float* w3    = (const float*)d_in[6];
    const float* b3    = (const float*)d_in[7];
    const int*   edges = (const int*)d_in[8];
    float* out = (float*)d_out;

    int src_sel = -1;  // pass 0 reads the (immutable) input tensor
    for (int p = 0; p < NPASS; ++p) {
        const int dst_sel = p & 1;  // 0,1,0,1,0 -> final result in buffer 0
        copyK<<<4096, 256, 0, stream>>>(nodes, src_sel, dst_sel);
        const int nthreads = NB * NE_TOT * 32;       // 32 lanes per edge
        scatterK<<<nthreads / 256, 256, 0, stream>>>(nodes, src_sel, dst_sel, edges);
        src_sel = dst_sel;
    }

    zeroPooledK<<<1, 1024, 0, stream>>>();
    poolK<<<dim3((NN + 127) / 128, NB), 128, 0, stream>>>(src_sel);
    headK<<<1, 256, 0, stream>>>(ptype, w1, b1, w2, b2, w3, b3, out);
}

// Round 2
// 487.702 us; speedup vs baseline: 29.8521x; 29.8521x over previous
//
#include <hip/hip_runtime.h>
#include <cmath>

#define NB 8
#define NN 20000
#define ND 128
#define NE_TOT 192000   /* 3 edge sets * 64000 edges, contiguous per batch */
#define NPASS 5

// Pooling-weight ping-pong buffers (the entire 5-pass propagation now runs on
// these 160000-float vectors instead of the 20M-float node tensor) + pooled.
__device__ float g_w0[NB * NN];
__device__ float g_w1[NB * NN];
__device__ float g_pooled[NB * ND];

__global__ void initK() {
    const int i = blockIdx.x * blockDim.x + threadIdx.x;
    if (i < NB * NN) g_w0[i] = 1.0f;
    if (i < NB * ND) g_pooled[i] = 0.0f;
}

// w_next = w_cur (identity part of I + A)
__global__ void copyWK(int src_sel) {
    const float* __restrict__ s = (src_sel == 0) ? g_w0 : g_w1;
    float* __restrict__ d       = (src_sel == 0) ? g_w1 : g_w0;
    const int i = blockIdx.x * blockDim.x + threadIdx.x;
    if (i < NB * NN) d[i] = s[i];
}

// Transpose propagation: per edge (dst,src): w_next[b][src] += w_cur[b][dst]
__global__ void scatterWK(const int* __restrict__ edges, int src_sel) {
    const float* __restrict__ w  = (src_sel == 0) ? g_w0 : g_w1;
    float* __restrict__ wn       = (src_sel == 0) ? g_w1 : g_w0;
    const int tid = blockIdx.x * blockDim.x + threadIdx.x;
    if (tid >= NB * NE_TOT) return;
    const int b = tid / NE_TOT;
    const int2 e = ((const int2*)edges)[tid];  // e.x = dst, e.y = src
    unsafeAtomicAdd(&wn[b * NN + e.y], w[b * NN + e.x]);
}

// pooled[b][d] = sum_n w[b][n] * nodes[b][n][d]  (single streaming read of nodes)
#define CHUNK 500
__global__ void poolWK(const float* __restrict__ nodes, int wsel) {
    const float* __restrict__ w = (wsel == 0) ? g_w0 : g_w1;
    const int b  = blockIdx.y;
    const int r0 = blockIdx.x * CHUNK;
    const int t  = threadIdx.x;   // 256
    const int dslot = t & 31;     // covers d = dslot*4 .. dslot*4+3
    const int rg    = t >> 5;     // row group 0..7
    float4 acc = {0.f, 0.f, 0.f, 0.f};
    const float4* __restrict__ base = (const float4*)(nodes + (size_t)b * NN * ND);
    for (int r = r0 + rg; r < r0 + CHUNK; r += 8) {
        const float wv = w[b * NN + r];
        const float4 v = base[(size_t)r * 32 + dslot];
        acc.x += wv * v.x; acc.y += wv * v.y; acc.z += wv * v.z; acc.w += wv * v.w;
    }
    __shared__ float4 red[256];
    red[t] = acc;
    __syncthreads();
    if (t < 32) {
        float4 s = red[t];
        for (int g = 1; g < 8; ++g) {
            const float4 o = red[g * 32 + t];
            s.x += o.x; s.y += o.y; s.z += o.z; s.w += o.w;
        }
        float* pp = &g_pooled[b * ND + dslot * 4];
        unsafeAtomicAdd(pp + 0, s.x);
        unsafeAtomicAdd(pp + 1, s.y);
        unsafeAtomicAdd(pp + 2, s.z);
        unsafeAtomicAdd(pp + 3, s.w);
    }
}

// log / nan->0 / relu / inf->finite_max / concat / MLP head. Tiny; one block.
__global__ void headK(const float* __restrict__ ptype,
                      const float* __restrict__ w1, const float* __restrict__ b1,
                      const float* __restrict__ w2, const float* __restrict__ b2,
                      const float* __restrict__ w3, const float* __restrict__ b3,
                      float* __restrict__ out) {
    __shared__ float sx[NB][ND + 1];  // y (128) + problem_type (1)
    __shared__ float sh1[NB][80];
    __shared__ float sh2[NB][80];
    const int t = threadIdx.x;  // blockDim.x == 256

    for (int i = t; i < NB * ND; i += 256) {
        const int b = i >> 7, d = i & 127;
        float y = logf(g_pooled[i]);
        if (isnan(y)) y = 0.0f;        // nan -> 0
        y = fmaxf(y, 0.0f);            // relu (also folds -inf -> 0)
        sx[b][d] = y;
    }
    __syncthreads();

    if (t < NB) {
        float fm = -INFINITY;
        for (int d = 0; d < ND; ++d) {
            const float y = sx[t][d];
            if (!isinf(y)) fm = fmaxf(fm, y);
        }
        for (int d = 0; d < ND; ++d)
            if (isinf(sx[t][d])) sx[t][d] = fm;  // +inf -> finite_max
        sx[t][ND] = ptype[t];
    }
    __syncthreads();

    for (int i = t; i < NB * 80; i += 256) {
        const int b = i / 80, j = i - b * 80;
        float s = b1[j];
        for (int k = 0; k < ND + 1; ++k) s += sx[b][k] * w1[k * 80 + j];
        sh1[b][j] = s > 0.0f ? s : 0.01f * s;  // leaky_relu
    }
    __syncthreads();

    for (int i = t; i < NB * 80; i += 256) {
        const int b = i / 80, j = i - b * 80;
        float s = b2[j];
        for (int k = 0; k < 80; ++k) s += sh1[b][k] * w2[k * 80 + j];
        sh2[b][j] = s > 0.0f ? s : 0.01f * s;
    }
    __syncthreads();

    for (int i = t; i < NB * 10; i += 256) {
        const int b = i / 10, j = i - b * 10;
        float s = b3[j];
        for (int k = 0; k < 80; ++k) s += sh2[b][k] * w3[k * 10 + j];
        out[b * 10 + j] = s;
    }
}

extern "C" void kernel_launch(void* const* d_in, const int* in_sizes, int n_in,
                              void* d_out, int out_size, void* d_ws, size_t ws_size,
                              hipStream_t stream) {
    const float* nodes = (const float*)d_in[0];
    const float* ptype = (const float*)d_in[1];
    const float* w1    = (const float*)d_in[2];
    const float* b1    = (const float*)d_in[3];
    const float* w2    = (const float*)d_in[4];
    const float* b2    = (const float*)d_in[5];
    const float* w3    = (const float*)d_in[6];
    const float* b3    = (const float*)d_in[7];
    const int*   edges = (const int*)d_in[8];
    float* out = (float*)d_out;

    initK<<<(NB * NN + 255) / 256, 256, 0, stream>>>();

    int sel = 0;  // current w lives in g_w0
    for (int p = 0; p < NPASS; ++p) {
        copyWK<<<(NB * NN + 255) / 256, 256, 0, stream>>>(sel);
        scatterWK<<<(NB * NE_TOT + 255) / 256, 256, 0, stream>>>(edges, sel);
        sel ^= 1;  // current w is now the other buffer
    }

    poolWK<<<dim3(NN / CHUNK, NB), 256, 0, stream>>>(nodes, sel);
    headK<<<1, 256, 0, stream>>>(ptype, w1, b1, w2, b2, w3, b3, out);
}

// Round 3
// 261.085 us; speedup vs baseline: 55.7631x; 1.8680x over previous
//
#include <hip/hip_runtime.h>
#include <cmath>

#define NB 8
#define NN 20000
#define ND 128
#define NE_TOT 192000   /* 3 edge sets * 64000 edges, contiguous per batch */
#define NPASS 5
#define NSUB 8                      /* sub-blocks per batch for the scatter */
#define EPB (NE_TOT / NSUB)         /* edges per block = 24000 */

// Weight ping-pong + per-(batch,sub) partial accumulators + pooled.
__device__ float g_w0[NB * NN];
__device__ float g_w1[NB * NN];
__device__ float g_partial[NB * NSUB * NN];   // 5.12 MB
__device__ float g_pooled[NB * ND];

__global__ void initK() {
    const int i = blockIdx.x * blockDim.x + threadIdx.x;
    if (i < NB * NN) g_w0[i] = 1.0f;
    if (i < NB * ND) g_pooled[i] = 0.0f;
}

// Per (batch, sub-chunk): accumulate w_cur[dst] into private LDS vector at
// [src], then write the full partial vector out with coalesced stores.
__global__ void scatterLDS(const int* __restrict__ edges, int src_sel) {
    extern __shared__ float acc[];  // NN floats = 80 KB
    const float* __restrict__ w = ((src_sel == 0) ? g_w0 : g_w1);
    const int b = blockIdx.x / NSUB;
    const int s = blockIdx.x % NSUB;
    const int t = threadIdx.x;      // 1024

    for (int i = t; i < NN; i += 1024) acc[i] = 0.0f;
    __syncthreads();

    const int2* __restrict__ ep =
        (const int2*)edges + (size_t)b * NE_TOT + (size_t)s * EPB;
    const float* __restrict__ wb = w + b * NN;
    for (int i = t; i < EPB; i += 1024) {
        const int2 e = ep[i];                 // e.x = dst, e.y = src
        unsafeAtomicAdd(&acc[e.y], wb[e.x]);  // ds_add_f32
    }
    __syncthreads();

    float* __restrict__ out = g_partial + ((size_t)b * NSUB + s) * NN;
    for (int i = t; i < NN; i += 1024) out[i] = acc[i];
}

// w_next = w_cur + sum_s partial[s]   (also plays the role of the identity copy)
__global__ void mergeK(int src_sel) {
    const float4* __restrict__ w  = (const float4*)((src_sel == 0) ? g_w0 : g_w1);
    float4* __restrict__ wn       = (float4*)((src_sel == 0) ? g_w1 : g_w0);
    const int i4 = blockIdx.x * blockDim.x + threadIdx.x;
    if (i4 >= NB * NN / 4) return;
    const int b  = i4 / (NN / 4);
    const int j4 = i4 - b * (NN / 4);
    float4 v = w[i4];
    for (int s = 0; s < NSUB; ++s) {
        const float4 p =
            ((const float4*)(g_partial + ((size_t)b * NSUB + s) * NN))[j4];
        v.x += p.x; v.y += p.y; v.z += p.z; v.w += p.w;
    }
    wn[i4] = v;
}

// pooled[b][d] = sum_n w[b][n] * nodes[b][n][d]  (single streaming read of nodes)
#define CHUNK 500
__global__ void poolWK(const float* __restrict__ nodes, int wsel) {
    const float* __restrict__ w = (wsel == 0) ? g_w0 : g_w1;
    const int b  = blockIdx.y;
    const int r0 = blockIdx.x * CHUNK;
    const int t  = threadIdx.x;   // 256
    const int dslot = t & 31;     // covers d = dslot*4 .. dslot*4+3
    const int rg    = t >> 5;     // row group 0..7
    float4 acc = {0.f, 0.f, 0.f, 0.f};
    const float4* __restrict__ base = (const float4*)(nodes + (size_t)b * NN * ND);
    for (int r = r0 + rg; r < r0 + CHUNK; r += 8) {
        const float wv = w[b * NN + r];
        const float4 v = base[(size_t)r * 32 + dslot];
        acc.x += wv * v.x; acc.y += wv * v.y; acc.z += wv * v.z; acc.w += wv * v.w;
    }
    __shared__ float4 red[256];
    red[t] = acc;
    __syncthreads();
    if (t < 32) {
        float4 s = red[t];
        for (int g = 1; g < 8; ++g) {
            const float4 o = red[g * 32 + t];
            s.x += o.x; s.y += o.y; s.z += o.z; s.w += o.w;
        }
        float* pp = &g_pooled[b * ND + dslot * 4];
        unsafeAtomicAdd(pp + 0, s.x);
        unsafeAtomicAdd(pp + 1, s.y);
        unsafeAtomicAdd(pp + 2, s.z);
        unsafeAtomicAdd(pp + 3, s.w);
    }
}

// log / nan->0 / relu / inf->finite_max / concat / MLP head. Tiny; one block.
__global__ void headK(const float* __restrict__ ptype,
                      const float* __restrict__ w1, const float* __restrict__ b1,
                      const float* __restrict__ w2, const float* __restrict__ b2,
                      const float* __restrict__ w3, const float* __restrict__ b3,
                      float* __restrict__ out) {
    __shared__ float sx[NB][ND + 1];  // y (128) + problem_type (1)
    __shared__ float sh1[NB][80];
    __shared__ float sh2[NB][80];
    const int t = threadIdx.x;  // blockDim.x == 256

    for (int i = t; i < NB * ND; i += 256) {
        const int b = i >> 7, d = i & 127;
        float y = logf(g_pooled[i]);
        if (isnan(y)) y = 0.0f;        // nan -> 0
        y = fmaxf(y, 0.0f);            // relu (also folds -inf -> 0)
        sx[b][d] = y;
    }
    __syncthreads();

    if (t < NB) {
        float fm = -INFINITY;
        for (int d = 0; d < ND; ++d) {
            const float y = sx[t][d];
            if (!isinf(y)) fm = fmaxf(fm, y);
        }
        for (int d = 0; d < ND; ++d)
            if (isinf(sx[t][d])) sx[t][d] = fm;  // +inf -> finite_max
        sx[t][ND] = ptype[t];
    }
    __syncthreads();

    for (int i = t; i < NB * 80; i += 256) {
        const int b = i / 80, j = i - b * 80;
        float s = b1[j];
        for (int k = 0; k < ND + 1; ++k) s += sx[b][k] * w1[k * 80 + j];
        sh1[b][j] = s > 0.0f ? s : 0.01f * s;  // leaky_relu
    }
    __syncthreads();

    for (int i = t; i < NB * 80; i += 256) {
        const int b = i / 80, j = i - b * 80;
        float s = b2[j];
        for (int k = 0; k < 80; ++k) s += sh1[b][k] * w2[k * 80 + j];
        sh2[b][j] = s > 0.0f ? s : 0.01f * s;
    }
    __syncthreads();

    for (int i = t; i < NB * 10; i += 256) {
        const int b = i / 10, j = i - b * 10;
        float s = b3[j];
        for (int k = 0; k < 80; ++k) s += sh2[b][k] * w3[k * 10 + j];
        out[b * 10 + j] = s;
    }
}

extern "C" void kernel_launch(void* const* d_in, const int* in_sizes, int n_in,
                              void* d_out, int out_size, void* d_ws, size_t ws_size,
                              hipStream_t stream) {
    const float* nodes = (const float*)d_in[0];
    const float* ptype = (const float*)d_in[1];
    const float* w1    = (const float*)d_in[2];
    const float* b1    = (const float*)d_in[3];
    const float* w2    = (const float*)d_in[4];
    const float* b2    = (const float*)d_in[5];
    const float* w3    = (const float*)d_in[6];
    const float* b3    = (const float*)d_in[7];
    const int*   edges = (const int*)d_in[8];
    float* out = (float*)d_out;

    initK<<<(NB * NN + 255) / 256, 256, 0, stream>>>();

    int sel = 0;  // current w lives in g_w0
    for (int p = 0; p < NPASS; ++p) {
        scatterLDS<<<NB * NSUB, 1024, NN * sizeof(float), stream>>>(edges, sel);
        mergeK<<<(NB * NN / 4 + 255) / 256, 256, 0, stream>>>(sel);
        sel ^= 1;  // current w is now the other buffer
    }

    poolWK<<<dim3(NN / CHUNK, NB), 256, 0, stream>>>(nodes, sel);
    headK<<<1, 256, 0, stream>>>(ptype, w1, b1, w2, b2, w3, b3, out);
}

// Round 4
// 193.420 us; speedup vs baseline: 75.2712x; 1.3498x over previous
//
#include <hip/hip_runtime.h>
#include <cmath>

#define NB 8
#define NN 20000
#define ND 128
#define NE_TOT 192000   /* 3 edge sets * 64000 edges, contiguous per batch */
#define NPASS 5
#define NSUB 32                     /* sub-blocks per batch for the scatter */
#define EPB (NE_TOT / NSUB)         /* edges per block = 6000 */

// Weight ping-pong + per-(batch,sub) partial accumulators + pooled.
__device__ float g_w0[NB * NN];
__device__ float g_w1[NB * NN];
__device__ float g_partial[(size_t)NB * NSUB * NN];   // 20.5 MB
__device__ float g_pooled[NB * ND];

__global__ void initK() {
    const int i = blockIdx.x * blockDim.x + threadIdx.x;
    if (i < NB * NN) g_w0[i] = 1.0f;
    if (i < NB * ND) g_pooled[i] = 0.0f;
}

// Per (batch, sub-chunk): accumulate w_cur[dst] into private LDS vector at
// [src], then write the full partial vector out with coalesced stores.
__global__ void scatterLDS(const int* __restrict__ edges, int src_sel) {
    extern __shared__ float acc[];  // NN floats = 80 KB
    const float* __restrict__ w = ((src_sel == 0) ? g_w0 : g_w1);
    const int b = blockIdx.x / NSUB;
    const int s = blockIdx.x % NSUB;
    const int t = threadIdx.x;      // 1024

    for (int i = t; i < NN; i += 1024) acc[i] = 0.0f;
    __syncthreads();

    const int2* __restrict__ ep =
        (const int2*)edges + (size_t)b * NE_TOT + (size_t)s * EPB;
    const float* __restrict__ wb = w + b * NN;
    for (int i = t; i < EPB; i += 1024) {
        const int2 e = ep[i];                 // e.x = dst, e.y = src
        unsafeAtomicAdd(&acc[e.y], wb[e.x]);  // ds_add_f32
    }
    __syncthreads();

    float* __restrict__ out = g_partial + ((size_t)b * NSUB + s) * NN;
    for (int i = t; i < NN; i += 1024) out[i] = acc[i];
}

// w_next = w_cur + sum_s partial[s]   (also plays the role of the identity copy)
__global__ void mergeK(int src_sel) {
    const float4* __restrict__ w  = (const float4*)((src_sel == 0) ? g_w0 : g_w1);
    float4* __restrict__ wn       = (float4*)((src_sel == 0) ? g_w1 : g_w0);
    const int i4 = blockIdx.x * blockDim.x + threadIdx.x;
    if (i4 >= NB * NN / 4) return;
    const int b  = i4 / (NN / 4);
    const int j4 = i4 - b * (NN / 4);
    float4 v = w[i4];
    for (int s = 0; s < NSUB; ++s) {
        const float4 p =
            ((const float4*)(g_partial + ((size_t)b * NSUB + s) * NN))[j4];
        v.x += p.x; v.y += p.y; v.z += p.z; v.w += p.w;
    }
    wn[i4] = v;
}

// pooled[b][d] = sum_n w[b][n] * nodes[b][n][d]  (single streaming read of nodes)
#define CHUNK 125
__global__ void poolWK(const float* __restrict__ nodes, int wsel) {
    const float* __restrict__ w = (wsel == 0) ? g_w0 : g_w1;
    const int b  = blockIdx.y;
    const int r0 = blockIdx.x * CHUNK;
    const int t  = threadIdx.x;   // 256
    const int dslot = t & 31;     // covers d = dslot*4 .. dslot*4+3
    const int rg    = t >> 5;     // row group 0..7
    float4 acc = {0.f, 0.f, 0.f, 0.f};
    const float4* __restrict__ base = (const float4*)(nodes + (size_t)b * NN * ND);
    for (int r = r0 + rg; r < r0 + CHUNK; r += 8) {
        const float wv = w[b * NN + r];
        const float4 v = base[(size_t)r * 32 + dslot];
        acc.x += wv * v.x; acc.y += wv * v.y; acc.z += wv * v.z; acc.w += wv * v.w;
    }
    __shared__ float4 red[256];
    red[t] = acc;
    __syncthreads();
    if (t < 32) {
        float4 s = red[t];
        for (int g = 1; g < 8; ++g) {
            const float4 o = red[g * 32 + t];
            s.x += o.x; s.y += o.y; s.z += o.z; s.w += o.w;
        }
        float* pp = &g_pooled[b * ND + dslot * 4];
        unsafeAtomicAdd(pp + 0, s.x);
        unsafeAtomicAdd(pp + 1, s.y);
        unsafeAtomicAdd(pp + 2, s.z);
        unsafeAtomicAdd(pp + 3, s.w);
    }
}

// log / nan->0 / relu / inf->finite_max / concat / MLP head. Tiny; one block.
__global__ void headK(const float* __restrict__ ptype,
                      const float* __restrict__ w1, const float* __restrict__ b1,
                      const float* __restrict__ w2, const float* __restrict__ b2,
                      const float* __restrict__ w3, const float* __restrict__ b3,
                      float* __restrict__ out) {
    __shared__ float sx[NB][ND + 1];  // y (128) + problem_type (1)
    __shared__ float sh1[NB][80];
    __shared__ float sh2[NB][80];
    const int t = threadIdx.x;  // blockDim.x == 256

    for (int i = t; i < NB * ND; i += 256) {
        const int b = i >> 7, d = i & 127;
        float y = logf(g_pooled[i]);
        if (isnan(y)) y = 0.0f;        // nan -> 0
        y = fmaxf(y, 0.0f);            // relu (also folds -inf -> 0)
        sx[b][d] = y;
    }
    __syncthreads();

    if (t < NB) {
        float fm = -INFINITY;
        for (int d = 0; d < ND; ++d) {
            const float y = sx[t][d];
            if (!isinf(y)) fm = fmaxf(fm, y);
        }
        for (int d = 0; d < ND; ++d)
            if (isinf(sx[t][d])) sx[t][d] = fm;  // +inf -> finite_max
        sx[t][ND] = ptype[t];
    }
    __syncthreads();

    for (int i = t; i < NB * 80; i += 256) {
        const int b = i / 80, j = i - b * 80;
        float s = b1[j];
        for (int k = 0; k < ND + 1; ++k) s += sx[b][k] * w1[k * 80 + j];
        sh1[b][j] = s > 0.0f ? s : 0.01f * s;  // leaky_relu
    }
    __syncthreads();

    for (int i = t; i < NB * 80; i += 256) {
        const int b = i / 80, j = i - b * 80;
        float s = b2[j];
        for (int k = 0; k < 80; ++k) s += sh1[b][k] * w2[k * 80 + j];
        sh2[b][j] = s > 0.0f ? s : 0.01f * s;
    }
    __syncthreads();

    for (int i = t; i < NB * 10; i += 256) {
        const int b = i / 10, j = i - b * 10;
        float s = b3[j];
        for (int k = 0; k < 80; ++k) s += sh2[b][k] * w3[k * 10 + j];
        out[b * 10 + j] = s;
    }
}

extern "C" void kernel_launch(void* const* d_in, const int* in_sizes, int n_in,
                              void* d_out, int out_size, void* d_ws, size_t ws_size,
                              hipStream_t stream) {
    const float* nodes = (const float*)d_in[0];
    const float* ptype = (const float*)d_in[1];
    const float* w1    = (const float*)d_in[2];
    const float* b1    = (const float*)d_in[3];
    const float* w2    = (const float*)d_in[4];
    const float* b2    = (const float*)d_in[5];
    const float* w3    = (const float*)d_in[6];
    const float* b3    = (const float*)d_in[7];
    const int*   edges = (const int*)d_in[8];
    float* out = (float*)d_out;

    initK<<<(NB * NN + 255) / 256, 256, 0, stream>>>();

    int sel = 0;  // current w lives in g_w0
    for (int p = 0; p < NPASS; ++p) {
        scatterLDS<<<NB * NSUB, 1024, NN * sizeof(float), stream>>>(edges, sel);
        mergeK<<<(NB * NN / 4 + 255) / 256, 256, 0, stream>>>(sel);
        sel ^= 1;  // current w is now the other buffer
    }

    poolWK<<<dim3(NN / CHUNK, NB), 256, 0, stream>>>(nodes, sel);
    headK<<<1, 256, 0, stream>>>(ptype, w1, b1, w2, b2, w3, b3, out);
}